// Round 6
// baseline (170.143 us; speedup 1.0000x reference)
//
#include <hip/hip_runtime.h>
#include <hip/hip_bf16.h>

typedef __bf16 bf16;
typedef _Float16 f16;
typedef __bf16 bf16x4 __attribute__((ext_vector_type(4)));
typedef __bf16 bf16x8 __attribute__((ext_vector_type(8)));
typedef _Float16 f16x2 __attribute__((ext_vector_type(2)));
typedef _Float16 f16x4 __attribute__((ext_vector_type(4)));
typedef _Float16 f16x8 __attribute__((ext_vector_type(8)));
typedef float floatx4 __attribute__((ext_vector_type(4)));

static __device__ __forceinline__ floatx4 mfma_bf16(bf16x8 a, bf16x8 b, floatx4 c) {
  return __builtin_amdgcn_mfma_f32_16x16x32_bf16(a, b, c, 0, 0, 0);
}
static __device__ __forceinline__ floatx4 mfma_f16k32(f16x8 a, f16x8 b, floatx4 c) {
  return __builtin_amdgcn_mfma_f32_16x16x32_f16(a, b, c, 0, 0, 0);
}

// async global->LDS, 16B per lane; LDS dest = wave-uniform base + lane*16
static __device__ __forceinline__ void async16(void* lds, const void* gp) {
  __builtin_amdgcn_global_load_lds(
      (const __attribute__((address_space(1))) void*)gp,
      (__attribute__((address_space(3))) void*)lds, 16, 0, 0);
}

static __device__ __forceinline__ bf16x8 cvt8(float4 f0, float4 f1) {
  bf16x8 r;
  r[0] = (bf16)f0.x; r[1] = (bf16)f0.y; r[2] = (bf16)f0.z; r[3] = (bf16)f0.w;
  r[4] = (bf16)f1.x; r[5] = (bf16)f1.y; r[6] = (bf16)f1.z; r[7] = (bf16)f1.w;
  return r;
}

#define HEADS 8
#define DIMH 64
#define DIM 512
#define SEQ 4096
#define HALF 2048
#define BATCH 2
#define MROWS (BATCH * SEQ)          // 8192
#define ELEMS ((size_t)MROWS * DIM)  // 4194304 per tensor
#define NPARTS 4

// SCALE * log2(e), folded into Q at the qkv epilogue
#define C2F (0.044194173824159216f * 1.4426950408889634f)

// ---------------------------------------------------------------------------
// Kernel 0 (prep): one launch for Xb = (bf16)X, WtQKV = (bf16)Wqkv^T,
// WtOUT = (bf16)Wout^T.  Branch is uniform per block.
// ---------------------------------------------------------------------------
__global__ __launch_bounds__(256)
void prep(const float* __restrict__ X, bf16* __restrict__ Xb,
          const float* __restrict__ wqkv, bf16* __restrict__ W1t,
          const float* __restrict__ wout, bf16* __restrict__ W2t) {
  __shared__ float tile[32][33];
  const int bid = blockIdx.x, t = threadIdx.x;
  if (bid < 2048) {  // xcvt: 2048 blocks x 2048 elems
    size_t i = ((size_t)bid * 256 + t) * 8;
    float4 f0 = *reinterpret_cast<const float4*>(X + i);
    float4 f1 = *reinterpret_cast<const float4*>(X + i + 4);
    *reinterpret_cast<bf16x8*>(Xb + i) = cvt8(f0, f1);
    return;
  }
  const float* src; bf16* dst; int N, id;
  if (bid < 2816) { id = bid - 2048; src = wqkv; dst = W1t; N = 1536; }
  else            { id = bid - 2816; src = wout; dst = W2t; N = 512; }
  const int nb = N / 32;
  const int n0 = (id % nb) * 32, k0 = (id / nb) * 32;
  const int r = t >> 3, c4 = (t & 7) * 4;
  float4 v = *reinterpret_cast<const float4*>(src + (size_t)(k0 + r) * N + n0 + c4);
  tile[r][c4 + 0] = v.x; tile[r][c4 + 1] = v.y;
  tile[r][c4 + 2] = v.z; tile[r][c4 + 3] = v.w;
  __syncthreads();
  bf16x4 o;
#pragma unroll
  for (int i = 0; i < 4; ++i) o[i] = (bf16)tile[c4 + i][r];
  *reinterpret_cast<bf16x4*>(dst + (size_t)(n0 + r) * DIM + k0 + c4) = o;
}

// ---------------------------------------------------------------------------
// Kernel 1: qkv = Xb @ Wqkv.  128x128 tile, DOUBLE-BUFFERED BK=32 async
// staging.  4 waves (2x2), 4x4 MFMA acc.
// Q (pre-scaled C2F), K -> [b][h][n][d] bf16; V -> Vt[b][h][d][n] f16.
// ---------------------------------------------------------------------------
__global__ __launch_bounds__(256)
void qkv_gemm(const bf16* __restrict__ Xb, const bf16* __restrict__ Wt,
              bf16* __restrict__ Qw, bf16* __restrict__ Kw, f16* __restrict__ Vt) {
  __shared__ __align__(16) char smem_raw[36864];
  // buf b: A at b*16384, B at b*16384+8192 (each 128x32 bf16 = 8 KB)

  const int m0 = blockIdx.x * 128, n0 = blockIdx.y * 128;
  const int t = threadIdx.x;
  const int wave = t >> 6, lane = t & 63, quad = lane >> 4, l16 = lane & 15;
  const int wr = wave >> 1, wc = wave & 1;

  f16 (*Ts)[72] = (f16(*)[72])(smem_raw + wave * 9216);  // epilogue alias

  floatx4 acc[4][4] = {};

  // granule g = it*256+t: row = g>>2, c8 = (g&3)*8; LDS byte = g*16
  auto issue = [&](int buf, int k0) {
    bf16* Asf = (bf16*)(smem_raw + buf * 16384);
    bf16* Bsf = Asf + 4096;
#pragma unroll
    for (int it = 0; it < 2; ++it) {
      int g = it * 256 + t, row = g >> 2, c8 = (g & 3) * 8;
      async16(Asf + (size_t)g * 8, Xb + (size_t)(m0 + row) * DIM + k0 + c8);
      async16(Bsf + (size_t)g * 8, Wt + (size_t)(n0 + row) * DIM + k0 + c8);
    }
  };

  issue(0, 0);
  int buf = 0;
#pragma unroll 1
  for (int k0 = 0; k0 < DIM; k0 += 32) {
    __syncthreads();  // drains this buf's loads (issued last step, covered)
    if (k0 + 32 < DIM) issue(buf ^ 1, k0 + 32);

    const bf16* Asf = (const bf16*)(smem_raw + buf * 16384);
    const bf16* Bsf = Asf + 4096;
    bf16x8 af[4], bfr[4];
#pragma unroll
    for (int mi = 0; mi < 4; ++mi)
      af[mi] = *reinterpret_cast<const bf16x8*>(
          Asf + (size_t)(wr * 64 + mi * 16 + l16) * 32 + quad * 8);
#pragma unroll
    for (int ni = 0; ni < 4; ++ni)
      bfr[ni] = *reinterpret_cast<const bf16x8*>(
          Bsf + (size_t)(wc * 64 + ni * 16 + l16) * 32 + quad * 8);
#pragma unroll
    for (int mi = 0; mi < 4; ++mi)
#pragma unroll
      for (int ni = 0; ni < 4; ++ni)
        acc[mi][ni] = mfma_bf16(af[mi], bfr[ni], acc[mi][ni]);
    buf ^= 1;
  }

  if (n0 < 1024) {  // pure Q or pure K tile
#pragma unroll
    for (int mi = 0; mi < 4; ++mi)
#pragma unroll
      for (int ni = 0; ni < 4; ++ni)
#pragma unroll
        for (int r = 0; r < 4; ++r) {
          int row = m0 + wr * 64 + mi * 16 + quad * 4 + r;
          int col = n0 + wc * 64 + ni * 16 + l16;
          int which = col >> 9, cc = col & 511;
          int head = cc >> 6, dim = cc & 63;
          int bb = row >> 12, nn = row & 4095;
          float val = acc[mi][ni][r];
          if (which == 0) val *= C2F;
          bf16* dst = which ? Kw : Qw;
          dst[(((size_t)(bb * HEADS + head)) * SEQ + nn) * DIMH + dim] = (bf16)val;
        }
  } else {  // V tile: per-wave 64x64 transpose through wave-private LDS
    __syncthreads();  // all waves done with GEMM LDS before aliasing as Ts
    int head = (n0 + wc * 64 - 1024) >> 6;
#pragma unroll
    for (int mi = 0; mi < 4; ++mi)
#pragma unroll
      for (int ni = 0; ni < 4; ++ni) {
        f16x4 pv;
#pragma unroll
        for (int r = 0; r < 4; ++r) pv[r] = (f16)acc[mi][ni][r];
        *reinterpret_cast<f16x4*>(&Ts[ni * 16 + l16][mi * 16 + quad * 4]) = pv;
      }
    int bb = m0 >> 12, nnb = (m0 + wr * 64) & 4095;
    size_t base = ((size_t)(bb * HEADS + head)) * DIMH;
#pragma unroll
    for (int it = 0; it < 8; ++it) {
      int idx = lane + it * 64;
      int d = idx >> 3, ns = (idx & 7) * 8;
      *reinterpret_cast<f16x8*>(Vt + (base + d) * SEQ + nnb + ns) =
          *reinterpret_cast<const f16x8*>(&Ts[d][ns]);
    }
  }
}

// ---------------------------------------------------------------------------
// Kernel 2: flash attention, KV-split-4.  ROUND-6: WAVE-AUTONOMOUS.
// Rounds 3/4/5 post-mortem: three different barrier schedules all land at
// ~50us with NO pipe >43% busy (MFMA 27, VALU 43, HBM 14, conflicts 0).
// Hypothesis: block barriers lockstep the ~10 resident waves/CU into the
// same phase (VALU together, MFMA together, wait together) -> pipes
// alternate idle/saturated.  Fix: 64-thread blocks, ZERO barriers; each
// wave owns a private 2-slot LDS ring (2 x 8KB = 16KB -> 10 blocks/CU) and
// paces itself with per-wave counted vmcnt(8) (8 DMA instr per 32-key
// tile).  Per-32-key math/staging/swizzle BIT-IDENTICAL to round 3
// (t -> it*64+lane).  Denominator now via MFMA against a ones-vector
// (replaces 16 VALU adds + 2 shuffle reduces; MFMA has headroom).
// Fixed-shift softmax: partials purely additive, combined in out_gemm.
// ---------------------------------------------------------------------------
__global__ __launch_bounds__(64, 4)
void attn_kernel(const bf16* __restrict__ Q, const bf16* __restrict__ K,
                 const f16* __restrict__ Vt, f16* __restrict__ Opart,
                 float* __restrict__ Lpart) {
  __shared__ __align__(16) char smem[16384];  // 2 slots x (K 4KB + V 4KB)

  // XCD-chunked decode: 8192 waves = xcd(8) x qw(128) x ghi(8); the 128
  // waves sharing one (h,b,part) K/V slice (128KB) stay on one XCD's L2.
  const int bid = blockIdx.x;
  const int xcd = bid & 7, rem = bid >> 3;
  const int qw = rem & 127, ghi = rem >> 7;
  const int g = ghi * 8 + xcd;              // 0..63 = h*8 + z
  const int h = g >> 3, z = g & 7;
  const int bb = z >> 2, part = z & 3;

  const int t = threadIdx.x;                // lane 0..63
  const int quad = t >> 4, l16 = t & 15;

  const size_t hb = ((size_t)(bb * HEADS + h)) * SEQ * DIMH;
  const int vhalf = (qw < 64) ? 0 : HALF;   // v_s for first-half queries
  const int kstart = HALF + part * 512;     // keys always from k_t
  const int vstart = vhalf + part * 512;
  const int q0 = qw * 32;

  // Q fragments (pre-scaled by C2F) -- issued FIRST (oldest vm ops)
  bf16x8 qa[2][2];
#pragma unroll
  for (int mt = 0; mt < 2; ++mt)
#pragma unroll
    for (int kc = 0; kc < 2; ++kc)
      qa[mt][kc] = *reinterpret_cast<const bf16x8*>(
          Q + hb + (size_t)(q0 + mt * 16 + l16) * DIMH + kc * 32 + quad * 8);

  floatx4 o_acc[2][4] = {};   // O^T[d=dsub*16+quad*4+r][query=l16] per mt
  floatx4 lacc[2] = {};       // denominator via ones-MFMA (rows all equal)

  // ---- DMA staging source addresses (granule g256 = it*64 + lane) ----
  // K tile [32 keys][64 d] bf16, rows 128B; LDS row r holds key kappa(r)
  // (sigma perm); phys 16B chunk p of row r holds logical d-chunk p^(r&7).
  const bf16* kSrcIt[4];
#pragma unroll
  for (int it = 0; it < 4; ++it) {
    int g256 = it * 64 + t;
    int r = g256 >> 3;                  // 0..31
    int rr = r & 15;
    int kappa = (rr >> 2) * 8 + (rr & 3) + ((r & 16) ? 4 : 0);
    int kchunk = (g256 & 7) ^ (r & 7);
    kSrcIt[it] = K + hb + (size_t)(kstart + kappa) * DIMH + kchunk * 8;
  }
  // V tile [64 d][32 keys] f16, rows 64B; phys chunk p of row d holds
  // logical key-chunk p^((d>>1)&3).  vchunk is it-invariant; vd(it)=vd0+16it.
  const int vd0 = t >> 2;                 // 0..15 for it=0
  const int vchunk = (t & 3) ^ ((vd0 >> 1) & 3);
  const f16* vSrc = Vt + hb + (size_t)vd0 * SEQ + vstart + vchunk * 8;

  auto issue = [&](int slot, int kc0) {
#pragma unroll
    for (int it = 0; it < 4; ++it)
      async16(smem + slot * 8192 + it * 1024 + t * 16,
              kSrcIt[it] + (size_t)kc0 * DIMH);
#pragma unroll
    for (int it = 0; it < 4; ++it)
      async16(smem + slot * 8192 + 4096 + it * 1024 + t * 16,
              vSrc + kc0 + (size_t)(it * 16) * SEQ);
  };

  // ---- swizzled LDS read offsets (constant per lane; same as round 3) ----
  const int koffA = l16 * 128 + ((quad ^ (l16 & 7)) * 16);  // rows 0..15
  const int voff = l16 * 64 + ((quad ^ ((l16 >> 1) & 3)) * 16);  // +dsub*1024

  f16x8 ones;
#pragma unroll
  for (int j = 0; j < 8; ++j) ones[j] = (f16)1.0f;

  auto compute = [&](const char* Kb) {
    const char* Vb = Kb + 4096;
    __builtin_amdgcn_s_setprio(1);
    bf16x8 kaA0 = *reinterpret_cast<const bf16x8*>(Kb + koffA);
    bf16x8 kaA1 = *reinterpret_cast<const bf16x8*>(Kb + (koffA ^ 64));
    bf16x8 kaB0 = *reinterpret_cast<const bf16x8*>(Kb + 2048 + koffA);
    bf16x8 kaB1 = *reinterpret_cast<const bf16x8*>(Kb + 2048 + (koffA ^ 64));

    f16x8 pbm[2];
#pragma unroll
    for (int mt = 0; mt < 2; ++mt) {
      floatx4 stA = {0.f, 0.f, 0.f, 0.f}, stB = {0.f, 0.f, 0.f, 0.f};
      stA = mfma_bf16(kaA0, qa[mt][0], stA);
      stA = mfma_bf16(kaA1, qa[mt][1], stA);
      stB = mfma_bf16(kaB0, qa[mt][0], stB);
      stB = mfma_bf16(kaB1, qa[mt][1], stB);
      f16x8 pb;
#pragma unroll
      for (int rr2 = 0; rr2 < 4; ++rr2) {
        pb[rr2] = (f16)__builtin_amdgcn_exp2f(stA[rr2]);
        pb[4 + rr2] = (f16)__builtin_amdgcn_exp2f(stB[rr2]);
      }
      pbm[mt] = pb;
      lacc[mt] = mfma_f16k32(ones, pb, lacc[mt]);  // denominator rows
    }
#pragma unroll
    for (int dsub = 0; dsub < 4; ++dsub) {
      f16x8 va = *reinterpret_cast<const f16x8*>(Vb + voff + dsub * 1024);
      o_acc[0][dsub] = mfma_f16k32(va, pbm[0], o_acc[0][dsub]);
      o_acc[1][dsub] = mfma_f16k32(va, pbm[1], o_acc[1][dsub]);
    }
    __builtin_amdgcn_s_setprio(0);
  };

  issue(0, 0);
  issue(1, 32);
#pragma unroll 1
  for (int i = 0; i < 16; i += 2) {
    // tile i (slot 0)
    asm volatile("s_waitcnt vmcnt(8)" ::: "memory");
    compute(smem);
    if (i + 2 < 16) {
      asm volatile("s_waitcnt lgkmcnt(0)" ::: "memory");
      __builtin_amdgcn_sched_barrier(0);
      issue(0, (i + 2) * 32);
    }
    // tile i+1 (slot 1)
    if (i + 1 == 15) asm volatile("s_waitcnt vmcnt(0)" ::: "memory");
    else             asm volatile("s_waitcnt vmcnt(8)" ::: "memory");
    compute(smem + 8192);
    if (i + 3 < 16) {
      asm volatile("s_waitcnt lgkmcnt(0)" ::: "memory");
      __builtin_amdgcn_sched_barrier(0);
      issue(1, (i + 3) * 32);
    }
  }

  // partial denominators + partial O out (lacc rows all equal sum_k P)
  f16* Op = Opart + (size_t)part * ELEMS;
  float* Lp = Lpart + (size_t)part * MROWS * HEADS;
#pragma unroll
  for (int mt = 0; mt < 2; ++mt) {
    int n = q0 + mt * 16 + l16;
    size_t rowidx = (size_t)(bb * SEQ + n);
    if (quad == 0) Lp[rowidx * HEADS + h] = lacc[mt][0];
    size_t rowbase = rowidx * DIM + h * DIMH;
#pragma unroll
    for (int dsub = 0; dsub < 4; ++dsub) {
      f16x4 ov;
#pragma unroll
      for (int r2 = 0; r2 < 4; ++r2) ov[r2] = (f16)o_acc[mt][dsub][r2];
      *reinterpret_cast<f16x4*>(Op + rowbase + dsub * 16 + quad * 4) = ov;
    }
  }
}

// ---------------------------------------------------------------------------
// Kernel 3: out = (sum_p O_p / sum_p L_p) @ Wout + b_out.  64x64 tile, BK=64,
// async B staging, combine fused into A-staging with O register prefetch.
// ---------------------------------------------------------------------------
__global__ __launch_bounds__(256)
void out_gemm(const f16* __restrict__ Opart, const float* __restrict__ Lpart,
              const bf16* __restrict__ Wt, const float* __restrict__ bias,
              float* __restrict__ out) {
  __shared__ __align__(16) bf16 Asf[64 * 64];   // [64][64] flat
  __shared__ __align__(16) bf16 Bsf[64 * 64];

  const int m0 = blockIdx.x * 64, n0 = blockIdx.y * 64;
  const int t = threadIdx.x;
  const int wave = t >> 6, lane = t & 63, quad = lane >> 4, l16 = lane & 15;
  const int m_off = (wave >> 1) * 32, n_off = (wave & 1) * 32;

  // per-thread staging coords (granule g = t + it*256)
  int srowi[2], sc8[2];
#pragma unroll
  for (int it = 0; it < 2; ++it) {
    int g = t + it * 256;
    srowi[it] = g >> 3; sc8[it] = (g & 7) * 8;
  }

  // preload 1/L per (staged row, head)
  float linv[2][8];
#pragma unroll
  for (int it = 0; it < 2; ++it) {
    size_t ar = (size_t)(m0 + srowi[it]);
#pragma unroll
    for (int hh = 0; hh < 8; ++hh) {
      float s = 0.f;
#pragma unroll
      for (int p = 0; p < NPARTS; ++p)
        s += Lpart[(size_t)p * MROWS * HEADS + ar * HEADS + hh];
      linv[it][hh] = 1.0f / s;
    }
  }

  floatx4 acc[2][2] = {};

  f16x8 oreg[2][NPARTS];
  auto loadO = [&](int k0) {
#pragma unroll
    for (int it = 0; it < 2; ++it) {
      size_t abase = (size_t)(m0 + srowi[it]) * DIM + k0 + sc8[it];
#pragma unroll
      for (int p = 0; p < NPARTS; ++p)
        oreg[it][p] = *reinterpret_cast<const f16x8*>(Opart + (size_t)p * ELEMS + abase);
    }
  };

  loadO(0);
#pragma unroll 1
  for (int k0 = 0; k0 < DIM; k0 += 64) {
#pragma unroll
    for (int it = 0; it < 2; ++it) {
      int g = t + it * 256;
      async16(Bsf + (size_t)g * 8, Wt + (size_t)(n0 + srowi[it]) * DIM + k0 + sc8[it]);
      float inv = linv[it][(k0 + sc8[it]) >> 6];
      bf16x8 a;
#pragma unroll
      for (int j = 0; j < 8; ++j)
        a[j] = (bf16)(((float)oreg[it][0][j] + (float)oreg[it][1][j] +
                       (float)oreg[it][2][j] + (float)oreg[it][3][j]) * inv);
      *reinterpret_cast<bf16x8*>(Asf + (size_t)g * 8) = a;
    }
    __syncthreads();  // drains async B + ds_writes
    int nk = k0 + 64; if (nk >= DIM) nk = 0;
    loadO(nk);  // prefetch next O slab during compute

#pragma unroll
    for (int kk = 0; kk < 2; ++kk) {
      bf16x8 a0 = *reinterpret_cast<const bf16x8*>(Asf + (size_t)(m_off + l16) * 64 + kk * 32 + quad * 8);
      bf16x8 a1 = *reinterpret_cast<const bf16x8*>(Asf + (size_t)(m_off + 16 + l16) * 64 + kk * 32 + quad * 8);
      bf16x8 b0 = *reinterpret_cast<const bf16x8*>(Bsf + (size_t)(n_off + l16) * 64 + kk * 32 + quad * 8);
      bf16x8 b1 = *reinterpret_cast<const bf16x8*>(Bsf + (size_t)(n_off + 16 + l16) * 64 + kk * 32 + quad * 8);
      acc[0][0] = mfma_bf16(a0, b0, acc[0][0]);
      acc[0][1] = mfma_bf16(a0, b1, acc[0][1]);
      acc[1][0] = mfma_bf16(a1, b0, acc[1][0]);
      acc[1][1] = mfma_bf16(a1, b1, acc[1][1]);
    }
    __syncthreads();
  }

#pragma unroll
  for (int mi = 0; mi < 2; ++mi)
#pragma unroll
    for (int ni = 0; ni < 2; ++ni)
#pragma unroll
      for (int r = 0; r < 4; ++r) {
        int row = m0 + m_off + mi * 16 + quad * 4 + r;
        int col = n0 + n_off + ni * 16 + l16;
        out[(size_t)row * DIM + col] = acc[mi][ni][r] + bias[col];
      }
}

extern "C" void kernel_launch(void* const* d_in, const int* in_sizes, int n_in,
                              void* d_out, int out_size, void* d_ws, size_t ws_size,
                              hipStream_t stream) {
  const float* x = (const float*)d_in[0];
  const float* wqkv = (const float*)d_in[1];
  const float* wout = (const float*)d_in[2];
  const float* bout = (const float*)d_in[3];
  float* out = (float*)d_out;

  char* ws = (char*)d_ws;
  f16* Opart = (f16*)ws;                     // 4 x 8 MB (part0 aliases Xb)
  bf16* Xb = (bf16*)ws;                      // 8 MB, consumed by qkv before attn
  bf16* Qw = (bf16*)(ws + ((size_t)32 << 20));  // 8 MB
  bf16* Kw = Qw + ELEMS;                     // 8 MB
  f16* Vt = (f16*)(Kw + ELEMS);              // 8 MB
  bf16* WtQKV = (bf16*)(Vt + ELEMS);         // 1.5 MB
  bf16* WtOUT = WtQKV + (size_t)1536 * 512;  // 0.5 MB
  float* Lpart = (float*)(WtOUT + (size_t)512 * 512);  // 4 x 256 KB

  prep<<<3072, 256, 0, stream>>>(x, Xb, wqkv, WtQKV, wout, WtOUT);
  qkv_gemm<<<dim3(MROWS / 128, 1536 / 128), 256, 0, stream>>>(Xb, WtQKV, Qw, Kw, Vt);
  attn_kernel<<<8192, 64, 0, stream>>>(Qw, Kw, Vt, Opart, Lpart);
  out_gemm<<<dim3(MROWS / 64, DIM / 64), 256, 0, stream>>>(Opart, Lpart, WtOUT, bout, out);
}

// Round 7
// 168.581 us; speedup vs baseline: 1.0093x; 1.0093x over previous
//
#include <hip/hip_runtime.h>
#include <hip/hip_bf16.h>

typedef __bf16 bf16;
typedef _Float16 f16;
typedef __bf16 bf16x4 __attribute__((ext_vector_type(4)));
typedef __bf16 bf16x8 __attribute__((ext_vector_type(8)));
typedef _Float16 f16x2 __attribute__((ext_vector_type(2)));
typedef _Float16 f16x4 __attribute__((ext_vector_type(4)));
typedef _Float16 f16x8 __attribute__((ext_vector_type(8)));
typedef float floatx4 __attribute__((ext_vector_type(4)));

static __device__ __forceinline__ floatx4 mfma_bf16(bf16x8 a, bf16x8 b, floatx4 c) {
  return __builtin_amdgcn_mfma_f32_16x16x32_bf16(a, b, c, 0, 0, 0);
}
static __device__ __forceinline__ floatx4 mfma_f16k32(f16x8 a, f16x8 b, floatx4 c) {
  return __builtin_amdgcn_mfma_f32_16x16x32_f16(a, b, c, 0, 0, 0);
}

// async global->LDS, 16B per lane; LDS dest = wave-uniform base + lane*16
static __device__ __forceinline__ void async16(void* lds, const void* gp) {
  __builtin_amdgcn_global_load_lds(
      (const __attribute__((address_space(1))) void*)gp,
      (__attribute__((address_space(3))) void*)lds, 16, 0, 0);
}

static __device__ __forceinline__ bf16x8 cvt8(float4 f0, float4 f1) {
  bf16x8 r;
  r[0] = (bf16)f0.x; r[1] = (bf16)f0.y; r[2] = (bf16)f0.z; r[3] = (bf16)f0.w;
  r[4] = (bf16)f1.x; r[5] = (bf16)f1.y; r[6] = (bf16)f1.z; r[7] = (bf16)f1.w;
  return r;
}

#define HEADS 8
#define DIMH 64
#define DIM 512
#define SEQ 4096
#define HALF 2048
#define BATCH 2
#define MROWS (BATCH * SEQ)          // 8192
#define ELEMS ((size_t)MROWS * DIM)  // 4194304 per tensor
#define NPARTS 4

// SCALE * log2(e), folded into Q at the qkv epilogue
#define C2F (0.044194173824159216f * 1.4426950408889634f)

// ---------------------------------------------------------------------------
// Kernel 0 (prep): one launch for Xb = (bf16)X, WtQKV = (bf16)Wqkv^T,
// WtOUT = (bf16)Wout^T.  Branch is uniform per block.
// ---------------------------------------------------------------------------
__global__ __launch_bounds__(256)
void prep(const float* __restrict__ X, bf16* __restrict__ Xb,
          const float* __restrict__ wqkv, bf16* __restrict__ W1t,
          const float* __restrict__ wout, bf16* __restrict__ W2t) {
  __shared__ float tile[32][33];
  const int bid = blockIdx.x, t = threadIdx.x;
  if (bid < 2048) {  // xcvt: 2048 blocks x 2048 elems
    size_t i = ((size_t)bid * 256 + t) * 8;
    float4 f0 = *reinterpret_cast<const float4*>(X + i);
    float4 f1 = *reinterpret_cast<const float4*>(X + i + 4);
    *reinterpret_cast<bf16x8*>(Xb + i) = cvt8(f0, f1);
    return;
  }
  const float* src; bf16* dst; int N, id;
  if (bid < 2816) { id = bid - 2048; src = wqkv; dst = W1t; N = 1536; }
  else            { id = bid - 2816; src = wout; dst = W2t; N = 512; }
  const int nb = N / 32;
  const int n0 = (id % nb) * 32, k0 = (id / nb) * 32;
  const int r = t >> 3, c4 = (t & 7) * 4;
  float4 v = *reinterpret_cast<const float4*>(src + (size_t)(k0 + r) * N + n0 + c4);
  tile[r][c4 + 0] = v.x; tile[r][c4 + 1] = v.y;
  tile[r][c4 + 2] = v.z; tile[r][c4 + 3] = v.w;
  __syncthreads();
  bf16x4 o;
#pragma unroll
  for (int i = 0; i < 4; ++i) o[i] = (bf16)tile[c4 + i][r];
  *reinterpret_cast<bf16x4*>(dst + (size_t)(n0 + r) * DIM + k0 + c4) = o;
}

// ---------------------------------------------------------------------------
// Kernel 1: qkv = Xb @ Wqkv.  128x128 tile, DOUBLE-BUFFERED BK=32 async
// staging.  4 waves (2x2), 4x4 MFMA acc.
// Q (pre-scaled C2F), K -> [b][h][n][d] bf16; V -> Vt[b][h][d][n] f16.
// ---------------------------------------------------------------------------
__global__ __launch_bounds__(256)
void qkv_gemm(const bf16* __restrict__ Xb, const bf16* __restrict__ Wt,
              bf16* __restrict__ Qw, bf16* __restrict__ Kw, f16* __restrict__ Vt) {
  __shared__ __align__(16) char smem_raw[36864];
  // buf b: A at b*16384, B at b*16384+8192 (each 128x32 bf16 = 8 KB)

  const int m0 = blockIdx.x * 128, n0 = blockIdx.y * 128;
  const int t = threadIdx.x;
  const int wave = t >> 6, lane = t & 63, quad = lane >> 4, l16 = lane & 15;
  const int wr = wave >> 1, wc = wave & 1;

  f16 (*Ts)[72] = (f16(*)[72])(smem_raw + wave * 9216);  // epilogue alias

  floatx4 acc[4][4] = {};

  // granule g = it*256+t: row = g>>2, c8 = (g&3)*8; LDS byte = g*16
  auto issue = [&](int buf, int k0) {
    bf16* Asf = (bf16*)(smem_raw + buf * 16384);
    bf16* Bsf = Asf + 4096;
#pragma unroll
    for (int it = 0; it < 2; ++it) {
      int g = it * 256 + t, row = g >> 2, c8 = (g & 3) * 8;
      async16(Asf + (size_t)g * 8, Xb + (size_t)(m0 + row) * DIM + k0 + c8);
      async16(Bsf + (size_t)g * 8, Wt + (size_t)(n0 + row) * DIM + k0 + c8);
    }
  };

  issue(0, 0);
  int buf = 0;
#pragma unroll 1
  for (int k0 = 0; k0 < DIM; k0 += 32) {
    __syncthreads();  // drains this buf's loads (issued last step, covered)
    if (k0 + 32 < DIM) issue(buf ^ 1, k0 + 32);

    const bf16* Asf = (const bf16*)(smem_raw + buf * 16384);
    const bf16* Bsf = Asf + 4096;
    bf16x8 af[4], bfr[4];
#pragma unroll
    for (int mi = 0; mi < 4; ++mi)
      af[mi] = *reinterpret_cast<const bf16x8*>(
          Asf + (size_t)(wr * 64 + mi * 16 + l16) * 32 + quad * 8);
#pragma unroll
    for (int ni = 0; ni < 4; ++ni)
      bfr[ni] = *reinterpret_cast<const bf16x8*>(
          Bsf + (size_t)(wc * 64 + ni * 16 + l16) * 32 + quad * 8);
#pragma unroll
    for (int mi = 0; mi < 4; ++mi)
#pragma unroll
      for (int ni = 0; ni < 4; ++ni)
        acc[mi][ni] = mfma_bf16(af[mi], bfr[ni], acc[mi][ni]);
    buf ^= 1;
  }

  if (n0 < 1024) {  // pure Q or pure K tile
#pragma unroll
    for (int mi = 0; mi < 4; ++mi)
#pragma unroll
      for (int ni = 0; ni < 4; ++ni)
#pragma unroll
        for (int r = 0; r < 4; ++r) {
          int row = m0 + wr * 64 + mi * 16 + quad * 4 + r;
          int col = n0 + wc * 64 + ni * 16 + l16;
          int which = col >> 9, cc = col & 511;
          int head = cc >> 6, dim = cc & 63;
          int bb = row >> 12, nn = row & 4095;
          float val = acc[mi][ni][r];
          if (which == 0) val *= C2F;
          bf16* dst = which ? Kw : Qw;
          dst[(((size_t)(bb * HEADS + head)) * SEQ + nn) * DIMH + dim] = (bf16)val;
        }
  } else {  // V tile: per-wave 64x64 transpose through wave-private LDS
    __syncthreads();  // all waves done with GEMM LDS before aliasing as Ts
    int head = (n0 + wc * 64 - 1024) >> 6;
#pragma unroll
    for (int mi = 0; mi < 4; ++mi)
#pragma unroll
      for (int ni = 0; ni < 4; ++ni) {
        f16x4 pv;
#pragma unroll
        for (int r = 0; r < 4; ++r) pv[r] = (f16)acc[mi][ni][r];
        *reinterpret_cast<f16x4*>(&Ts[ni * 16 + l16][mi * 16 + quad * 4]) = pv;
      }
    int bb = m0 >> 12, nnb = (m0 + wr * 64) & 4095;
    size_t base = ((size_t)(bb * HEADS + head)) * DIMH;
#pragma unroll
    for (int it = 0; it < 8; ++it) {
      int idx = lane + it * 64;
      int d = idx >> 3, ns = (idx & 7) * 8;
      *reinterpret_cast<f16x8*>(Vt + (base + d) * SEQ + nnb + ns) =
          *reinterpret_cast<const f16x8*>(&Ts[d][ns]);
    }
  }
}

// ---------------------------------------------------------------------------
// Kernel 2: flash attention, KV-split-4.  EXACT round-3 kernel (best
// measured: 49.4-49.6us, VGPR 64 -> 8 waves/SIMD).  Rounds 4-6 established:
// any VGPR >64 or geometry change loses occupancy with no latency win; this
// structure is the attn plateau.  DMA+swizzle staging, conflicts = 0.
// Fixed-shift softmax: partials purely additive, combined in out_gemm.
// ---------------------------------------------------------------------------
__global__ __launch_bounds__(256)
void attn_kernel(const bf16* __restrict__ Q, const bf16* __restrict__ K,
                 const f16* __restrict__ Vt, f16* __restrict__ Opart,
                 float* __restrict__ Lpart) {
  __shared__ __align__(16) char smem[16384];  // 2 bufs x (K 4KB + V 4KB)

  const int qt = blockIdx.x;                          // 0..31: 128-query tile
  const int h = blockIdx.y;
  const int bb = blockIdx.z >> 2, part = blockIdx.z & 3;
  const int t = threadIdx.x;
  const int wave = t >> 6, lane = t & 63, quad = lane >> 4, l16 = lane & 15;

  const size_t hb = ((size_t)(bb * HEADS + h)) * SEQ * DIMH;
  const int vhalf = (qt < 16) ? 0 : HALF;   // v_s for first-half queries
  const int kstart = HALF + part * 512;     // keys always from k_t
  const int vstart = vhalf + part * 512;
  const int q0 = qt * 128 + wave * 32;

  // Q fragments (pre-scaled by C2F)
  bf16x8 qa[2][2];
#pragma unroll
  for (int mt = 0; mt < 2; ++mt)
#pragma unroll
    for (int kc = 0; kc < 2; ++kc)
      qa[mt][kc] = *reinterpret_cast<const bf16x8*>(
          Q + hb + (size_t)(q0 + mt * 16 + l16) * DIMH + kc * 32 + quad * 8);

  floatx4 o_acc[2][4] = {};   // O^T[d=dsub*16+quad*4+r][query=l16] per mt
  float l_acc[2] = {0.f, 0.f};

  // ---- DMA staging source addresses (computed once) ----
  const int r = t >> 3;                   // K LDS row 0..31
  const int rr = r & 15;
  const int kappa = (rr >> 2) * 8 + (rr & 3) + ((r & 16) ? 4 : 0);
  const int kchunk = (t & 7) ^ (r & 7);
  const bf16* kSrc = K + hb + (size_t)(kstart + kappa) * DIMH + kchunk * 8;

  const int vd = t >> 2;                  // V LDS row (d) 0..63
  const int vchunk = (t & 3) ^ ((vd >> 1) & 3);
  const f16* vSrc = Vt + hb + (size_t)vd * SEQ + vstart + vchunk * 8;

  char* ldsK = smem + t * 16;             // linear DMA dest (buf0)
  char* ldsV = smem + 4096 + t * 16;

  auto issue = [&](int buf, int kc0) {
    async16(ldsK + buf * 8192, kSrc + (size_t)kc0 * DIMH);
    async16(ldsV + buf * 8192, vSrc + kc0);
  };

  // ---- swizzled LDS read offsets (constant per lane) ----
  const int koffA = l16 * 128 + ((quad ^ (l16 & 7)) * 16);  // rows 0..15
  const int voff = l16 * 64 + ((quad ^ ((l16 >> 1) & 3)) * 16);  // +dsub*1024

  auto compute = [&](const char* Kb) {
    const char* Vb = Kb + 4096;
    bf16x8 kaA0 = *reinterpret_cast<const bf16x8*>(Kb + koffA);
    bf16x8 kaA1 = *reinterpret_cast<const bf16x8*>(Kb + (koffA ^ 64));
    bf16x8 kaB0 = *reinterpret_cast<const bf16x8*>(Kb + 2048 + koffA);
    bf16x8 kaB1 = *reinterpret_cast<const bf16x8*>(Kb + 2048 + (koffA ^ 64));

    f16x8 pbm[2];
#pragma unroll
    for (int mt = 0; mt < 2; ++mt) {
      floatx4 stA = {0.f, 0.f, 0.f, 0.f}, stB = {0.f, 0.f, 0.f, 0.f};
      stA = mfma_bf16(kaA0, qa[mt][0], stA);
      stA = mfma_bf16(kaA1, qa[mt][1], stA);
      stB = mfma_bf16(kaB0, qa[mt][0], stB);
      stB = mfma_bf16(kaB1, qa[mt][1], stB);
      float ls = l_acc[mt];
      f16x8 pb;
#pragma unroll
      for (int rr2 = 0; rr2 < 4; ++rr2) {
        float pA = __builtin_amdgcn_exp2f(stA[rr2]);
        float pB = __builtin_amdgcn_exp2f(stB[rr2]);
        ls += pA + pB;
        pb[rr2] = (f16)pA;
        pb[4 + rr2] = (f16)pB;
      }
      l_acc[mt] = ls;
      pbm[mt] = pb;
    }
#pragma unroll
    for (int dsub = 0; dsub < 4; ++dsub) {
      f16x8 va = *reinterpret_cast<const f16x8*>(Vb + voff + dsub * 1024);
      o_acc[0][dsub] = mfma_f16k32(va, pbm[0], o_acc[0][dsub]);
      o_acc[1][dsub] = mfma_f16k32(va, pbm[1], o_acc[1][dsub]);
    }
  };

  issue(0, 0);
#pragma unroll 1
  for (int kc0 = 0; kc0 < 512; kc0 += 64) {
    asm volatile("s_waitcnt vmcnt(0)" ::: "memory");
    __syncthreads();                      // buf0 DMA done; buf1 reads done
    issue(1, kc0 + 32);
    compute(smem);                        // buf0 = keys [kc0, kc0+32)
    asm volatile("s_waitcnt vmcnt(0)" ::: "memory");
    __syncthreads();                      // buf1 DMA done; buf0 reads done
    if (kc0 + 64 < 512) issue(0, kc0 + 64);
    compute(smem + 8192);                 // buf1 = keys [kc0+32, kc0+64)
  }

  // partial denominators + partial O out
  f16* Op = Opart + (size_t)part * ELEMS;
  float* Lp = Lpart + (size_t)part * MROWS * HEADS;
#pragma unroll
  for (int mt = 0; mt < 2; ++mt) {
    float v = l_acc[mt];
    v += __shfl_xor(v, 16);
    v += __shfl_xor(v, 32);
    int n = q0 + mt * 16 + l16;
    size_t rowidx = (size_t)(bb * SEQ + n);
    if (quad == 0) Lp[rowidx * HEADS + h] = v;
    size_t rowbase = rowidx * DIM + h * DIMH;
#pragma unroll
    for (int dsub = 0; dsub < 4; ++dsub) {
      f16x4 ov;
#pragma unroll
      for (int r2 = 0; r2 < 4; ++r2) ov[r2] = (f16)o_acc[mt][dsub][r2];
      *reinterpret_cast<f16x4*>(Op + rowbase + dsub * 16 + quad * 4) = ov;
    }
  }
}

// ---------------------------------------------------------------------------
// Kernel 3: out = (sum_p O_p / sum_p L_p) @ Wout + b_out.  ROUND-7 REBUILD.
// Old 64x64/BK=64 tile had (a) 128B LDS row stride with NO swizzle -> every
// ds_read_b128 16-lane phase on one bank (16-way, m136: ~5.7x LDS cost),
// (b) 8 MFMA per 8 staged b128 reads (poor density).  New: 128x64 tile
// (grid 512, 2 blocks/CU), BK=64 == DIMH so each K-step is exactly one head
// (1/L is a single reg), acc 4x2 (16 MFMA/step/wave), XOR swizzle
// chunk^=(row&7) on A (write-side, reg-staged) and B (source-side, DMA) --
// the scheme attn validated to zero conflicts.
// ---------------------------------------------------------------------------
__global__ __launch_bounds__(256)
void out_gemm(const f16* __restrict__ Opart, const float* __restrict__ Lpart,
              const bf16* __restrict__ Wt, const float* __restrict__ bias,
              float* __restrict__ out) {
  __shared__ __align__(16) bf16 Asf[128 * 64];  // swizzled [128][64]
  __shared__ __align__(16) bf16 Bsf[64 * 64];   // swizzled [64][64]

  const int m0 = blockIdx.x * 128, n0 = blockIdx.y * 64;
  const int t = threadIdx.x;
  const int wave = t >> 6, lane = t & 63, quad = lane >> 4, l16 = lane & 15;
  const int m_off = (wave >> 1) * 64, n_off = (wave & 1) * 32;

  // staging coords: granule g = t + it*256; row = g>>3, chunk = g&7
  const int srow = t >> 3, schunk = t & 7;   // it adds 32 rows

  // preload 1/L per (A-staging row, head): linv[it][head]
  float linv[4][8];
#pragma unroll
  for (int it = 0; it < 4; ++it) {
    size_t ar = (size_t)(m0 + srow + it * 32);
#pragma unroll
    for (int hh = 0; hh < 8; ++hh) {
      float s = 0.f;
#pragma unroll
      for (int p = 0; p < NPARTS; ++p)
        s += Lpart[(size_t)p * MROWS * HEADS + ar * HEADS + hh];
      linv[it][hh] = 1.0f / s;
    }
  }

  floatx4 acc[4][2] = {};

  f16x8 oreg[4][NPARTS];
  auto loadO = [&](int k0) {
#pragma unroll
    for (int it = 0; it < 4; ++it) {
      size_t abase = (size_t)(m0 + srow + it * 32) * DIM + k0 + schunk * 8;
#pragma unroll
      for (int p = 0; p < NPARTS; ++p)
        oreg[it][p] = *reinterpret_cast<const f16x8*>(Opart + (size_t)p * ELEMS + abase);
    }
  };

  loadO(0);
#pragma unroll 1
  for (int k0 = 0; k0 < DIM; k0 += 64) {
    const int head = k0 >> 6;  // BK == DIMH: one head per K-step
    // B staging via DMA, source-side swizzle (LDS dest linear)
#pragma unroll
    for (int it = 0; it < 2; ++it) {
      int g = t + it * 256, brow = g >> 3;
      int bchunk = (g & 7) ^ (brow & 7);
      async16(Bsf + (size_t)g * 8,
              Wt + (size_t)(n0 + brow) * DIM + k0 + bchunk * 8);
    }
    // A staging: combine parts, write-side swizzle
#pragma unroll
    for (int it = 0; it < 4; ++it) {
      int arow = srow + it * 32;
      float inv = linv[it][head];
      bf16x8 a;
#pragma unroll
      for (int j = 0; j < 8; ++j)
        a[j] = (bf16)(((float)oreg[it][0][j] + (float)oreg[it][1][j] +
                       (float)oreg[it][2][j] + (float)oreg[it][3][j]) * inv);
      *reinterpret_cast<bf16x8*>(
          Asf + (size_t)arow * 64 + ((schunk ^ (arow & 7)) * 8)) = a;
    }
    __syncthreads();  // drains async B + ds_writes
    int nk = k0 + 64; if (nk >= DIM) nk = 0;
    loadO(nk);  // prefetch next O slab during compute

#pragma unroll
    for (int kk = 0; kk < 2; ++kk) {
      bf16x8 af[4], bfr[2];
#pragma unroll
      for (int mi = 0; mi < 4; ++mi) {
        int row = m_off + mi * 16 + l16;
        af[mi] = *reinterpret_cast<const bf16x8*>(
            Asf + (size_t)row * 64 + (((kk * 4 + quad) ^ (row & 7)) * 8));
      }
#pragma unroll
      for (int ni = 0; ni < 2; ++ni) {
        int row = n_off + ni * 16 + l16;
        bfr[ni] = *reinterpret_cast<const bf16x8*>(
            Bsf + (size_t)row * 64 + (((kk * 4 + quad) ^ (row & 7)) * 8));
      }
#pragma unroll
      for (int mi = 0; mi < 4; ++mi)
#pragma unroll
        for (int ni = 0; ni < 2; ++ni)
          acc[mi][ni] = mfma_bf16(af[mi], bfr[ni], acc[mi][ni]);
    }
    __syncthreads();
  }

#pragma unroll
  for (int mi = 0; mi < 4; ++mi)
#pragma unroll
    for (int ni = 0; ni < 2; ++ni)
#pragma unroll
      for (int r = 0; r < 4; ++r) {
        int row = m0 + m_off + mi * 16 + quad * 4 + r;
        int col = n0 + n_off + ni * 16 + l16;
        out[(size_t)row * DIM + col] = acc[mi][ni][r] + bias[col];
      }
}

extern "C" void kernel_launch(void* const* d_in, const int* in_sizes, int n_in,
                              void* d_out, int out_size, void* d_ws, size_t ws_size,
                              hipStream_t stream) {
  const float* x = (const float*)d_in[0];
  const float* wqkv = (const float*)d_in[1];
  const float* wout = (const float*)d_in[2];
  const float* bout = (const float*)d_in[3];
  float* out = (float*)d_out;

  char* ws = (char*)d_ws;
  f16* Opart = (f16*)ws;                     // 4 x 8 MB (part0 aliases Xb)
  bf16* Xb = (bf16*)ws;                      // 8 MB, consumed by qkv before attn
  bf16* Qw = (bf16*)(ws + ((size_t)32 << 20));  // 8 MB
  bf16* Kw = Qw + ELEMS;                     // 8 MB
  f16* Vt = (f16*)(Kw + ELEMS);              // 8 MB
  bf16* WtQKV = (bf16*)(Vt + ELEMS);         // 1.5 MB
  bf16* WtOUT = WtQKV + (size_t)1536 * 512;  // 0.5 MB
  float* Lpart = (float*)(WtOUT + (size_t)512 * 512);  // 4 x 256 KB

  prep<<<3072, 256, 0, stream>>>(x, Xb, wqkv, WtQKV, wout, WtOUT);
  qkv_gemm<<<dim3(MROWS / 128, 1536 / 128), 256, 0, stream>>>(Xb, WtQKV, Qw, Kw, Vt);
  attn_kernel<<<dim3(SEQ / 128, HEADS, BATCH * NPARTS), 256, 0, stream>>>(Qw, Kw, Vt, Opart, Lpart);
  out_gemm<<<dim3(MROWS / 128, DIM / 64), 256, 0, stream>>>(Opart, Lpart, WtOUT, bout, out);
}

// Round 8
// 155.776 us; speedup vs baseline: 1.0922x; 1.0822x over previous
//
#include <hip/hip_runtime.h>
#include <hip/hip_bf16.h>

typedef __bf16 bf16;
typedef _Float16 f16;
typedef __bf16 bf16x4 __attribute__((ext_vector_type(4)));
typedef __bf16 bf16x8 __attribute__((ext_vector_type(8)));
typedef _Float16 f16x2 __attribute__((ext_vector_type(2)));
typedef _Float16 f16x4 __attribute__((ext_vector_type(4)));
typedef _Float16 f16x8 __attribute__((ext_vector_type(8)));
typedef float floatx4 __attribute__((ext_vector_type(4)));

static __device__ __forceinline__ floatx4 mfma_bf16(bf16x8 a, bf16x8 b, floatx4 c) {
  return __builtin_amdgcn_mfma_f32_16x16x32_bf16(a, b, c, 0, 0, 0);
}
static __device__ __forceinline__ floatx4 mfma_f16k32(f16x8 a, f16x8 b, floatx4 c) {
  return __builtin_amdgcn_mfma_f32_16x16x32_f16(a, b, c, 0, 0, 0);
}

// async global->LDS, 16B per lane; LDS dest = wave-uniform base + lane*16
static __device__ __forceinline__ void async16(void* lds, const void* gp) {
  __builtin_amdgcn_global_load_lds(
      (const __attribute__((address_space(1))) void*)gp,
      (__attribute__((address_space(3))) void*)lds, 16, 0, 0);
}

static __device__ __forceinline__ bf16x8 cvt8(float4 f0, float4 f1) {
  bf16x8 r;
  r[0] = (bf16)f0.x; r[1] = (bf16)f0.y; r[2] = (bf16)f0.z; r[3] = (bf16)f0.w;
  r[4] = (bf16)f1.x; r[5] = (bf16)f1.y; r[6] = (bf16)f1.z; r[7] = (bf16)f1.w;
  return r;
}

#define HEADS 8
#define DIMH 64
#define DIM 512
#define SEQ 4096
#define HALF 2048
#define BATCH 2
#define MROWS (BATCH * SEQ)          // 8192
#define ELEMS ((size_t)MROWS * DIM)  // 4194304 per tensor
#define NPARTS 4

// SCALE * log2(e), folded into Q at the qkv epilogue
#define C2F (0.044194173824159216f * 1.4426950408889634f)

// ---------------------------------------------------------------------------
// Kernel 0 (prep): one launch for Xb = (bf16)X, WtQKV = (bf16)Wqkv^T,
// WtOUT = (bf16)Wout^T.  Branch is uniform per block.
// ---------------------------------------------------------------------------
__global__ __launch_bounds__(256)
void prep(const float* __restrict__ X, bf16* __restrict__ Xb,
          const float* __restrict__ wqkv, bf16* __restrict__ W1t,
          const float* __restrict__ wout, bf16* __restrict__ W2t) {
  __shared__ float tile[32][33];
  const int bid = blockIdx.x, t = threadIdx.x;
  if (bid < 2048) {  // xcvt: 2048 blocks x 2048 elems
    size_t i = ((size_t)bid * 256 + t) * 8;
    float4 f0 = *reinterpret_cast<const float4*>(X + i);
    float4 f1 = *reinterpret_cast<const float4*>(X + i + 4);
    *reinterpret_cast<bf16x8*>(Xb + i) = cvt8(f0, f1);
    return;
  }
  const float* src; bf16* dst; int N, id;
  if (bid < 2816) { id = bid - 2048; src = wqkv; dst = W1t; N = 1536; }
  else            { id = bid - 2816; src = wout; dst = W2t; N = 512; }
  const int nb = N / 32;
  const int n0 = (id % nb) * 32, k0 = (id / nb) * 32;
  const int r = t >> 3, c4 = (t & 7) * 4;
  float4 v = *reinterpret_cast<const float4*>(src + (size_t)(k0 + r) * N + n0 + c4);
  tile[r][c4 + 0] = v.x; tile[r][c4 + 1] = v.y;
  tile[r][c4 + 2] = v.z; tile[r][c4 + 3] = v.w;
  __syncthreads();
  bf16x4 o;
#pragma unroll
  for (int i = 0; i < 4; ++i) o[i] = (bf16)tile[c4 + i][r];
  *reinterpret_cast<bf16x4*>(dst + (size_t)(n0 + r) * DIM + k0 + c4) = o;
}

// ---------------------------------------------------------------------------
// Kernel 1: qkv = Xb @ Wqkv.  128x128 tile, DOUBLE-BUFFERED BK=32 async
// staging.  4 waves (2x2), 4x4 MFMA acc.
// Q (pre-scaled C2F), K -> [b][h][n][d] bf16; V -> Vt[b][h][d][n] f16.
// ---------------------------------------------------------------------------
__global__ __launch_bounds__(256)
void qkv_gemm(const bf16* __restrict__ Xb, const bf16* __restrict__ Wt,
              bf16* __restrict__ Qw, bf16* __restrict__ Kw, f16* __restrict__ Vt) {
  __shared__ __align__(16) char smem_raw[36864];
  // buf b: A at b*16384, B at b*16384+8192 (each 128x32 bf16 = 8 KB)

  const int m0 = blockIdx.x * 128, n0 = blockIdx.y * 128;
  const int t = threadIdx.x;
  const int wave = t >> 6, lane = t & 63, quad = lane >> 4, l16 = lane & 15;
  const int wr = wave >> 1, wc = wave & 1;

  f16 (*Ts)[72] = (f16(*)[72])(smem_raw + wave * 9216);  // epilogue alias

  floatx4 acc[4][4] = {};

  // granule g = it*256+t: row = g>>2, c8 = (g&3)*8; LDS byte = g*16
  auto issue = [&](int buf, int k0) {
    bf16* Asf = (bf16*)(smem_raw + buf * 16384);
    bf16* Bsf = Asf + 4096;
#pragma unroll
    for (int it = 0; it < 2; ++it) {
      int g = it * 256 + t, row = g >> 2, c8 = (g & 3) * 8;
      async16(Asf + (size_t)g * 8, Xb + (size_t)(m0 + row) * DIM + k0 + c8);
      async16(Bsf + (size_t)g * 8, Wt + (size_t)(n0 + row) * DIM + k0 + c8);
    }
  };

  issue(0, 0);
  int buf = 0;
#pragma unroll 1
  for (int k0 = 0; k0 < DIM; k0 += 32) {
    __syncthreads();  // drains this buf's loads (issued last step, covered)
    if (k0 + 32 < DIM) issue(buf ^ 1, k0 + 32);

    const bf16* Asf = (const bf16*)(smem_raw + buf * 16384);
    const bf16* Bsf = Asf + 4096;
    bf16x8 af[4], bfr[4];
#pragma unroll
    for (int mi = 0; mi < 4; ++mi)
      af[mi] = *reinterpret_cast<const bf16x8*>(
          Asf + (size_t)(wr * 64 + mi * 16 + l16) * 32 + quad * 8);
#pragma unroll
    for (int ni = 0; ni < 4; ++ni)
      bfr[ni] = *reinterpret_cast<const bf16x8*>(
          Bsf + (size_t)(wc * 64 + ni * 16 + l16) * 32 + quad * 8);
#pragma unroll
    for (int mi = 0; mi < 4; ++mi)
#pragma unroll
      for (int ni = 0; ni < 4; ++ni)
        acc[mi][ni] = mfma_bf16(af[mi], bfr[ni], acc[mi][ni]);
    buf ^= 1;
  }

  if (n0 < 1024) {  // pure Q or pure K tile
#pragma unroll
    for (int mi = 0; mi < 4; ++mi)
#pragma unroll
      for (int ni = 0; ni < 4; ++ni)
#pragma unroll
        for (int r = 0; r < 4; ++r) {
          int row = m0 + wr * 64 + mi * 16 + quad * 4 + r;
          int col = n0 + wc * 64 + ni * 16 + l16;
          int which = col >> 9, cc = col & 511;
          int head = cc >> 6, dim = cc & 63;
          int bb = row >> 12, nn = row & 4095;
          float val = acc[mi][ni][r];
          if (which == 0) val *= C2F;
          bf16* dst = which ? Kw : Qw;
          dst[(((size_t)(bb * HEADS + head)) * SEQ + nn) * DIMH + dim] = (bf16)val;
        }
  } else {  // V tile: per-wave 64x64 transpose through wave-private LDS
    __syncthreads();  // all waves done with GEMM LDS before aliasing as Ts
    int head = (n0 + wc * 64 - 1024) >> 6;
#pragma unroll
    for (int mi = 0; mi < 4; ++mi)
#pragma unroll
      for (int ni = 0; ni < 4; ++ni) {
        f16x4 pv;
#pragma unroll
        for (int r = 0; r < 4; ++r) pv[r] = (f16)acc[mi][ni][r];
        *reinterpret_cast<f16x4*>(&Ts[ni * 16 + l16][mi * 16 + quad * 4]) = pv;
      }
    int bb = m0 >> 12, nnb = (m0 + wr * 64) & 4095;
    size_t base = ((size_t)(bb * HEADS + head)) * DIMH;
#pragma unroll
    for (int it = 0; it < 8; ++it) {
      int idx = lane + it * 64;
      int d = idx >> 3, ns = (idx & 7) * 8;
      *reinterpret_cast<f16x8*>(Vt + (base + d) * SEQ + nnb + ns) =
          *reinterpret_cast<const f16x8*>(&Ts[d][ns]);
    }
  }
}

// ---------------------------------------------------------------------------
// Kernel 2: flash attention, KV-split-4.  EXACT round-3 kernel (best
// measured: 49.4-49.6us, VGPR 64 -> 8 waves/SIMD).  Rounds 4-6 established:
// any VGPR >64 or geometry change loses occupancy with no latency win; this
// structure is the attn plateau.  DMA+swizzle staging, conflicts = 0.
// Fixed-shift softmax: partials purely additive, combined in out_gemm.
// ---------------------------------------------------------------------------
__global__ __launch_bounds__(256)
void attn_kernel(const bf16* __restrict__ Q, const bf16* __restrict__ K,
                 const f16* __restrict__ Vt, f16* __restrict__ Opart,
                 float* __restrict__ Lpart) {
  __shared__ __align__(16) char smem[16384];  // 2 bufs x (K 4KB + V 4KB)

  const int qt = blockIdx.x;                          // 0..31: 128-query tile
  const int h = blockIdx.y;
  const int bb = blockIdx.z >> 2, part = blockIdx.z & 3;
  const int t = threadIdx.x;
  const int wave = t >> 6, lane = t & 63, quad = lane >> 4, l16 = lane & 15;

  const size_t hb = ((size_t)(bb * HEADS + h)) * SEQ * DIMH;
  const int vhalf = (qt < 16) ? 0 : HALF;   // v_s for first-half queries
  const int kstart = HALF + part * 512;     // keys always from k_t
  const int vstart = vhalf + part * 512;
  const int q0 = qt * 128 + wave * 32;

  // Q fragments (pre-scaled by C2F)
  bf16x8 qa[2][2];
#pragma unroll
  for (int mt = 0; mt < 2; ++mt)
#pragma unroll
    for (int kc = 0; kc < 2; ++kc)
      qa[mt][kc] = *reinterpret_cast<const bf16x8*>(
          Q + hb + (size_t)(q0 + mt * 16 + l16) * DIMH + kc * 32 + quad * 8);

  floatx4 o_acc[2][4] = {};   // O^T[d=dsub*16+quad*4+r][query=l16] per mt
  float l_acc[2] = {0.f, 0.f};

  // ---- DMA staging source addresses (computed once) ----
  const int r = t >> 3;                   // K LDS row 0..31
  const int rr = r & 15;
  const int kappa = (rr >> 2) * 8 + (rr & 3) + ((r & 16) ? 4 : 0);
  const int kchunk = (t & 7) ^ (r & 7);
  const bf16* kSrc = K + hb + (size_t)(kstart + kappa) * DIMH + kchunk * 8;

  const int vd = t >> 2;                  // V LDS row (d) 0..63
  const int vchunk = (t & 3) ^ ((vd >> 1) & 3);
  const f16* vSrc = Vt + hb + (size_t)vd * SEQ + vstart + vchunk * 8;

  char* ldsK = smem + t * 16;             // linear DMA dest (buf0)
  char* ldsV = smem + 4096 + t * 16;

  auto issue = [&](int buf, int kc0) {
    async16(ldsK + buf * 8192, kSrc + (size_t)kc0 * DIMH);
    async16(ldsV + buf * 8192, vSrc + kc0);
  };

  // ---- swizzled LDS read offsets (constant per lane) ----
  const int koffA = l16 * 128 + ((quad ^ (l16 & 7)) * 16);  // rows 0..15
  const int voff = l16 * 64 + ((quad ^ ((l16 >> 1) & 3)) * 16);  // +dsub*1024

  auto compute = [&](const char* Kb) {
    const char* Vb = Kb + 4096;
    bf16x8 kaA0 = *reinterpret_cast<const bf16x8*>(Kb + koffA);
    bf16x8 kaA1 = *reinterpret_cast<const bf16x8*>(Kb + (koffA ^ 64));
    bf16x8 kaB0 = *reinterpret_cast<const bf16x8*>(Kb + 2048 + koffA);
    bf16x8 kaB1 = *reinterpret_cast<const bf16x8*>(Kb + 2048 + (koffA ^ 64));

    f16x8 pbm[2];
#pragma unroll
    for (int mt = 0; mt < 2; ++mt) {
      floatx4 stA = {0.f, 0.f, 0.f, 0.f}, stB = {0.f, 0.f, 0.f, 0.f};
      stA = mfma_bf16(kaA0, qa[mt][0], stA);
      stA = mfma_bf16(kaA1, qa[mt][1], stA);
      stB = mfma_bf16(kaB0, qa[mt][0], stB);
      stB = mfma_bf16(kaB1, qa[mt][1], stB);
      float ls = l_acc[mt];
      f16x8 pb;
#pragma unroll
      for (int rr2 = 0; rr2 < 4; ++rr2) {
        float pA = __builtin_amdgcn_exp2f(stA[rr2]);
        float pB = __builtin_amdgcn_exp2f(stB[rr2]);
        ls += pA + pB;
        pb[rr2] = (f16)pA;
        pb[4 + rr2] = (f16)pB;
      }
      l_acc[mt] = ls;
      pbm[mt] = pb;
    }
#pragma unroll
    for (int dsub = 0; dsub < 4; ++dsub) {
      f16x8 va = *reinterpret_cast<const f16x8*>(Vb + voff + dsub * 1024);
      o_acc[0][dsub] = mfma_f16k32(va, pbm[0], o_acc[0][dsub]);
      o_acc[1][dsub] = mfma_f16k32(va, pbm[1], o_acc[1][dsub]);
    }
  };

  issue(0, 0);
#pragma unroll 1
  for (int kc0 = 0; kc0 < 512; kc0 += 64) {
    asm volatile("s_waitcnt vmcnt(0)" ::: "memory");
    __syncthreads();                      // buf0 DMA done; buf1 reads done
    issue(1, kc0 + 32);
    compute(smem);                        // buf0 = keys [kc0, kc0+32)
    asm volatile("s_waitcnt vmcnt(0)" ::: "memory");
    __syncthreads();                      // buf1 DMA done; buf0 reads done
    if (kc0 + 64 < 512) issue(0, kc0 + 64);
    compute(smem + 8192);                 // buf1 = keys [kc0+32, kc0+64)
  }

  // partial denominators + partial O out
  f16* Op = Opart + (size_t)part * ELEMS;
  float* Lp = Lpart + (size_t)part * MROWS * HEADS;
#pragma unroll
  for (int mt = 0; mt < 2; ++mt) {
    float v = l_acc[mt];
    v += __shfl_xor(v, 16);
    v += __shfl_xor(v, 32);
    int n = q0 + mt * 16 + l16;
    size_t rowidx = (size_t)(bb * SEQ + n);
    if (quad == 0) Lp[rowidx * HEADS + h] = v;
    size_t rowbase = rowidx * DIM + h * DIMH;
#pragma unroll
    for (int dsub = 0; dsub < 4; ++dsub) {
      f16x4 ov;
#pragma unroll
      for (int r2 = 0; r2 < 4; ++r2) ov[r2] = (f16)o_acc[mt][dsub][r2];
      *reinterpret_cast<f16x4*>(Op + rowbase + dsub * 16 + quad * 4) = ov;
    }
  }
}

// ---------------------------------------------------------------------------
// Kernel 3: out = (sum_p O_p / sum_p L_p) @ Wout + b_out.  ROUND-3 STRUCTURE
// (64x64 tile, BK=64, 1024 blocks -- 4 clean runs at 156-160 total) with ONE
// surgical change: XOR chunk swizzle.  Desk-check (round 7): with 128B row
// stride, bank = (chunk*4+w)%32 (row drops out) and each quad's 16 lanes
// read the SAME chunk -> 16-way conflict on all 8 ds_read_b128/K-step.
// Swizzle: phys chunk p of row r holds logical p^(r&7).  B: folded into the
// DMA source address (LDS dest linear).  A: folded into the ds_write
// address (combine still operates on logical data -> linv indexing
// unchanged).  Reads XOR with row&7 -> per-quad chunks span 8 values ->
// 2-way = free (m136).  Writes were already 2-way.
// ---------------------------------------------------------------------------
__global__ __launch_bounds__(256)
void out_gemm(const f16* __restrict__ Opart, const float* __restrict__ Lpart,
              const bf16* __restrict__ Wt, const float* __restrict__ bias,
              float* __restrict__ out) {
  __shared__ __align__(16) bf16 Asf[64 * 64];   // [64][64], chunk-swizzled
  __shared__ __align__(16) bf16 Bsf[64 * 64];   // [64][64], chunk-swizzled

  const int m0 = blockIdx.x * 64, n0 = blockIdx.y * 64;
  const int t = threadIdx.x;
  const int wave = t >> 6, lane = t & 63, quad = lane >> 4, l16 = lane & 15;
  const int m_off = (wave >> 1) * 32, n_off = (wave & 1) * 32;

  // per-thread staging coords (granule g = t + it*256)
  int srowi[2], sc8[2], swz8[2];
#pragma unroll
  for (int it = 0; it < 2; ++it) {
    int g = t + it * 256;
    srowi[it] = g >> 3; sc8[it] = (g & 7) * 8;
    swz8[it] = ((g & 7) ^ (srowi[it] & 7)) * 8;   // swizzled chunk offset
  }

  // preload 1/L per (staged row, head)
  float linv[2][8];
#pragma unroll
  for (int it = 0; it < 2; ++it) {
    size_t ar = (size_t)(m0 + srowi[it]);
#pragma unroll
    for (int hh = 0; hh < 8; ++hh) {
      float s = 0.f;
#pragma unroll
      for (int p = 0; p < NPARTS; ++p)
        s += Lpart[(size_t)p * MROWS * HEADS + ar * HEADS + hh];
      linv[it][hh] = 1.0f / s;
    }
  }

  floatx4 acc[2][2] = {};

  f16x8 oreg[2][NPARTS];
  auto loadO = [&](int k0) {
#pragma unroll
    for (int it = 0; it < 2; ++it) {
      size_t abase = (size_t)(m0 + srowi[it]) * DIM + k0 + sc8[it];
#pragma unroll
      for (int p = 0; p < NPARTS; ++p)
        oreg[it][p] = *reinterpret_cast<const f16x8*>(Opart + (size_t)p * ELEMS + abase);
    }
  };

  loadO(0);
#pragma unroll 1
  for (int k0 = 0; k0 < DIM; k0 += 64) {
#pragma unroll
    for (int it = 0; it < 2; ++it) {
      // B: DMA with SOURCE-side swizzle (LDS dest linear: phys chunk g&7
      // receives logical chunk (g&7)^(row&7))
      async16(Bsf + (size_t)(t + it * 256) * 8,
              Wt + (size_t)(n0 + srowi[it]) * DIM + k0 + swz8[it]);
      // A: combine logical chunk sc8, write to swizzled phys address
      float inv = linv[it][(k0 + sc8[it]) >> 6];
      bf16x8 a;
#pragma unroll
      for (int j = 0; j < 8; ++j)
        a[j] = (bf16)(((float)oreg[it][0][j] + (float)oreg[it][1][j] +
                       (float)oreg[it][2][j] + (float)oreg[it][3][j]) * inv);
      *reinterpret_cast<bf16x8*>(Asf + (size_t)srowi[it] * 64 + swz8[it]) = a;
    }
    __syncthreads();  // drains async B + ds_writes
    int nk = k0 + 64; if (nk >= DIM) nk = 0;
    loadO(nk);  // prefetch next O slab during compute

#pragma unroll
    for (int kk = 0; kk < 2; ++kk) {
      const int c = kk * 4 + quad;                 // logical chunk
      const int ra0 = m_off + l16, ra1 = m_off + 16 + l16;
      const int rb0 = n_off + l16, rb1 = n_off + 16 + l16;
      bf16x8 a0 = *reinterpret_cast<const bf16x8*>(Asf + (size_t)ra0 * 64 + ((c ^ (ra0 & 7)) * 8));
      bf16x8 a1 = *reinterpret_cast<const bf16x8*>(Asf + (size_t)ra1 * 64 + ((c ^ (ra1 & 7)) * 8));
      bf16x8 b0 = *reinterpret_cast<const bf16x8*>(Bsf + (size_t)rb0 * 64 + ((c ^ (rb0 & 7)) * 8));
      bf16x8 b1 = *reinterpret_cast<const bf16x8*>(Bsf + (size_t)rb1 * 64 + ((c ^ (rb1 & 7)) * 8));
      acc[0][0] = mfma_bf16(a0, b0, acc[0][0]);
      acc[0][1] = mfma_bf16(a0, b1, acc[0][1]);
      acc[1][0] = mfma_bf16(a1, b0, acc[1][0]);
      acc[1][1] = mfma_bf16(a1, b1, acc[1][1]);
    }
    __syncthreads();
  }

#pragma unroll
  for (int mi = 0; mi < 2; ++mi)
#pragma unroll
    for (int ni = 0; ni < 2; ++ni)
#pragma unroll
      for (int r = 0; r < 4; ++r) {
        int row = m0 + m_off + mi * 16 + quad * 4 + r;
        int col = n0 + n_off + ni * 16 + l16;
        out[(size_t)row * DIM + col] = acc[mi][ni][r] + bias[col];
      }
}

extern "C" void kernel_launch(void* const* d_in, const int* in_sizes, int n_in,
                              void* d_out, int out_size, void* d_ws, size_t ws_size,
                              hipStream_t stream) {
  const float* x = (const float*)d_in[0];
  const float* wqkv = (const float*)d_in[1];
  const float* wout = (const float*)d_in[2];
  const float* bout = (const float*)d_in[3];
  float* out = (float*)d_out;

  char* ws = (char*)d_ws;
  f16* Opart = (f16*)ws;                     // 4 x 8 MB (part0 aliases Xb)
  bf16* Xb = (bf16*)ws;                      // 8 MB, consumed by qkv before attn
  bf16* Qw = (bf16*)(ws + ((size_t)32 << 20));  // 8 MB
  bf16* Kw = Qw + ELEMS;                     // 8 MB
  f16* Vt = (f16*)(Kw + ELEMS);              // 8 MB
  bf16* WtQKV = (bf16*)(Vt + ELEMS);         // 1.5 MB
  bf16* WtOUT = WtQKV + (size_t)1536 * 512;  // 0.5 MB
  float* Lpart = (float*)(WtOUT + (size_t)512 * 512);  // 4 x 256 KB

  prep<<<3072, 256, 0, stream>>>(x, Xb, wqkv, WtQKV, wout, WtOUT);
  qkv_gemm<<<dim3(MROWS / 128, 1536 / 128), 256, 0, stream>>>(Xb, WtQKV, Qw, Kw, Vt);
  attn_kernel<<<dim3(SEQ / 128, HEADS, BATCH * NPARTS), 256, 0, stream>>>(Qw, Kw, Vt, Opart, Lpart);
  out_gemm<<<dim3(MROWS / 64, DIM / 64), 256, 0, stream>>>(Opart, Lpart, WtOUT, bout, out);
}